// Round 10
// baseline (261.015 us; speedup 1.0000x reference)
//
#include <hip/hip_runtime.h>
#include <hip/hip_bf16.h>
#include <hip/hip_fp16.h>

#define IN_DIM 4096
#define OUT_DIM 4096
#define HAD_SCALE_F 0.08838834764831845f   // 2^-3.5

typedef int   i32x4 __attribute__((ext_vector_type(4)));
typedef float f32x4 __attribute__((ext_vector_type(4)));

// ---------------------------------------------------------------------------
// Kernel A: per-row blockwise Hadamard (FWHT over 128-blocks), scale,
// per-row absmax -> symmetric int8 quantization (s_a = max/127), and
// QUANTIZED row sum rowsum[m] = s_a * sum(q).
// ---------------------------------------------------------------------------
__global__ __launch_bounds__(256)
void had_rows_q(const float* __restrict__ x, int* __restrict__ aq,
                float* __restrict__ rowsum, float* __restrict__ srow)
{
    __shared__ float lds[IN_DIM];
    __shared__ float wmx[4];
    __shared__ int   wqs[4];
    const int tid = threadIdx.x;
    const size_t row = blockIdx.x;
    const float* xr = x + row * IN_DIM;

    #pragma unroll
    for (int v = 0; v < 4; ++v) {
        const int idx = v * 1024 + tid * 4;
        *(float4*)&lds[idx] = *(const float4*)&xr[idx];
    }
    __syncthreads();

    #pragma unroll
    for (int s = 0; s < 7; ++s) {
        const int stride = 1 << s;
        #pragma unroll
        for (int t = 0; t < 8; ++t) {
            const int p   = t * 256 + tid;
            const int blk = p >> 6;
            const int q   = p & 63;
            const int i   = ((q & ~(stride - 1)) << 1) | (q & (stride - 1));
            const int lo  = blk * 128 + i;
            const float u  = lds[lo];
            const float v2 = lds[lo + stride];
            lds[lo]          = u + v2;
            lds[lo + stride] = u - v2;
        }
        __syncthreads();
    }

    float e[16];
    float smax = 0.f;
    #pragma unroll
    for (int v = 0; v < 4; ++v) {
        const int idx = v * 1024 + tid * 4;
        const float4 f = *(const float4*)&lds[idx];
        e[v*4+0] = f.x * HAD_SCALE_F; e[v*4+1] = f.y * HAD_SCALE_F;
        e[v*4+2] = f.z * HAD_SCALE_F; e[v*4+3] = f.w * HAD_SCALE_F;
        smax = fmaxf(smax, fmaxf(fmaxf(fabsf(e[v*4+0]), fabsf(e[v*4+1])),
                                 fmaxf(fabsf(e[v*4+2]), fabsf(e[v*4+3]))));
    }
    #pragma unroll
    for (int off = 32; off > 0; off >>= 1)
        smax = fmaxf(smax, __shfl_down(smax, off, 64));
    if ((tid & 63) == 0) wmx[tid >> 6] = smax;
    __syncthreads();
    const float mx  = fmaxf(fmaxf(wmx[0], wmx[1]), fmaxf(wmx[2], wmx[3]));
    const float inv = (mx > 0.f) ? 127.0f / mx : 0.f;
    const float sa  = mx * (1.0f / 127.0f);

    int qsum = 0;
    #pragma unroll
    for (int v = 0; v < 4; ++v) {
        const int idx = v * 1024 + tid * 4;
        const int q0 = (int)rintf(e[v*4+0] * inv);
        const int q1 = (int)rintf(e[v*4+1] * inv);
        const int q2 = (int)rintf(e[v*4+2] * inv);
        const int q3 = (int)rintf(e[v*4+3] * inv);
        qsum += (q0 + q1) + (q2 + q3);
        aq[(row * IN_DIM + idx) >> 2] =
            (q0 & 0xFF) | ((q1 & 0xFF) << 8) | ((q2 & 0xFF) << 16) | (q3 << 24);
    }
    #pragma unroll
    for (int off = 32; off > 0; off >>= 1) qsum += __shfl_down(qsum, off, 64);
    if ((tid & 63) == 0) wqs[tid >> 6] = qsum;
    __syncthreads();
    if (tid == 0) {
        rowsum[row] = sa * (float)((wqs[0] + wqs[1]) + (wqs[2] + wqs[3]));
        srow[row]   = sa;
    }
}

// ---------------------------------------------------------------------------
// Kernel B: unpack int4 nibbles -> int8 weight matrix [OUT][IN] row-major.
// ---------------------------------------------------------------------------
__global__ __launch_bounds__(256)
void unpack_w8(const int* __restrict__ wp, signed char* __restrict__ wf8)
{
    const int gid = blockIdx.x * 256 + threadIdx.x;
    const int n   = gid >> 9;
    const int k0  = (gid & 511) * 8;
    const int4 p  = *(const int4*)(wp + (size_t)n * (IN_DIM / 2) + (k0 >> 1));
    const unsigned lo = (unsigned)(p.x & 15) | ((unsigned)((p.x >> 4) & 15) << 8)
                      | ((unsigned)(p.y & 15) << 16) | ((unsigned)((p.y >> 4) & 15) << 24);
    const unsigned hi = (unsigned)(p.z & 15) | ((unsigned)((p.z >> 4) & 15) << 8)
                      | ((unsigned)(p.w & 15) << 16) | ((unsigned)((p.w >> 4) & 15) << 24);
    *(uint2*)(wf8 + (size_t)n * IN_DIM + k0) = make_uint2(lo, hi);
}

// ---------------------------------------------------------------------------
// Kernel C: 256x256 int8 GEMM, 4-window schedule, FULLY register-pipelined
// (round-10 change). Round 8 was half-pipelined: Q(mq,1) consumed B nq1
// fragments loaded in the SAME window -> mid-window lgkm drain serialized
// the LDS and MFMA bursts (window 2542cy ~= 1306 MFMA + LDS, additive).
// Now every ds_read in window W feeds MFMA in window W+1 only:
//   bfr0 (nq0) loaded W2 (b1) / W4 (b0'), overwrite ordered after Q(1,0);
//   b2A/b2B (nq1, double-buffered): b0 nq1 -> b2A (W4/prologue),
//   b1 nq1 -> b2B (W2).
// Consuming-MFMA (W+1) forces lgkm completion >=1 barrier before the read
// region's restage (W+2) — the invariant round 9 violated. Stage sets,
// vm counts (W1:2/0, W2:4, W3:2, W4:4) and barriers identical to round 8.
// ---------------------------------------------------------------------------
#define NT (IN_DIM / 128)   // 32 K-regions
#define NI (NT / 2)         // 16 iterations, 2 regions each

#define BAR()        asm volatile("s_barrier" ::: "memory")
#define WAIT_VM(N)   asm volatile("s_waitcnt vmcnt(" #N ")" ::: "memory")

// LDS: A0 @ 0, B0 @ 32768, A1 @ 65536, B1 @ 98304 (each 32 KiB = 256 rows x 128 B)
#define STAGE_A(p, R, kt) __builtin_amdgcn_global_load_lds( \
    (const __attribute__((address_space(1))) void*)(sA + (((size_t)(R)) << 18) + (((size_t)((kt) & 31)) << 7)), \
    (__attribute__((address_space(3))) void*)(smem + (p) * 65536 + (R) * 8192 + dstA), 16, 0, 0)
#define STAGE_B(p, R, kt) __builtin_amdgcn_global_load_lds( \
    (const __attribute__((address_space(1))) void*)(sB + (((size_t)(R)) << 18) + (((size_t)((kt) & 31)) << 7)), \
    (__attribute__((address_space(3))) void*)(smem + (p) * 65536 + (R) * 8192 + dstB), 16, 0, 0)

#define LDA(p, mq, mi, kb) (*(const i32x4*)(smem + (p)*65536 + (mq)*8192 + (mi)*2048 + aOffK[kb]))
#define LDB(p, nq, ni, kb) (*(const i32x4*)(smem + (p)*65536 + (nq)*4096 + (ni)*2048 + bOffK[kb]))

#define LOAD_A_TO(dst, p, mq) do { \
    _Pragma("unroll") for (int mi = 0; mi < 4; ++mi) { \
        dst[mi][0] = LDA(p, mq, mi, 0); \
        dst[mi][1] = LDA(p, mq, mi, 1); \
    } } while (0)

#define LOAD_B_TO(dst, p, nq) do { \
    _Pragma("unroll") for (int ni = 0; ni < 2; ++ni) { \
        dst[ni][0] = LDB(p, nq, ni, 0); \
        dst[ni][1] = LDB(p, nq, ni, 1); \
    } } while (0)

#define MFMA_Q2(abuf, bset, mq, nq) do { \
    __builtin_amdgcn_s_setprio(1); \
    _Pragma("unroll") for (int mi = 0; mi < 4; ++mi) \
    _Pragma("unroll") for (int ni = 0; ni < 2; ++ni) \
    _Pragma("unroll") for (int kb = 0; kb < 2; ++kb) \
        acc[(mq)*4+mi][(nq)*2+ni] = __builtin_amdgcn_mfma_i32_16x16x64_i8( \
            abuf[mi][kb], bset[ni][kb], acc[(mq)*4+mi][(nq)*2+ni], 0, 0, 0); \
    __builtin_amdgcn_s_setprio(0); \
} while (0)

__global__ __launch_bounds__(512, 2)
void gemm_i8(const signed char* __restrict__ Aq, const signed char* __restrict__ Bw,
             const float* __restrict__ wscale, const float* __restrict__ wadd,
             const float* __restrict__ bias, const float* __restrict__ rowsum,
             const float* __restrict__ srow, float* __restrict__ out)
{
    __shared__ char smem[131072];

    const int tid  = threadIdx.x;
    const int lane = tid & 63;
    const int w    = tid >> 6;     // wave 0..7
    const int wm   = w >> 2;       // 0..1
    const int wn   = w & 3;        // 0..3

    // XCD-aware bijective swizzle: 512 wgs, 8 XCDs, 64 per XCD
    const int bid = blockIdx.x;
    const int wg  = (bid & 7) * 64 + (bid >> 3);
    const int m0  = (wg >> 4) * 256;   // M/256 = 32
    const int n0  = (wg & 15) * 256;   // N/256 = 16

    // ---- staging addresses (pre-swizzled source, linear LDS dest) ----
    const int rt = tid >> 3;
    const int ct = (tid & 7) ^ (rt & 7);
    const signed char* sA = Aq + (size_t)(m0 + rt) * IN_DIM + ct * 16;
    const signed char* sB = Bw + (size_t)(n0 + rt) * IN_DIM + ct * 16;
    const int dstA = w * 1024;
    const int dstB = 32768 + w * 1024;

    // ---- fragment read offsets (swizzled) ----
    const int l15 = lane & 15, g = lane >> 4, l7 = lane & 7;
    const int s0 = (g ^ l7) << 4;
    int aOffK[2], bOffK[2];
    aOffK[0] = (wm * 128 + l15) * 128 + s0;
    aOffK[1] = (wm * 128 + l15) * 128 + (s0 ^ 64);
    bOffK[0] = 32768 + (wn * 64 + l15) * 128 + s0;
    bOffK[1] = 32768 + (wn * 64 + l15) * 128 + (s0 ^ 64);

    i32x4 afrA[4][2], afrB[4][2];
    i32x4 bfr0[2][2], b2A[2][2], b2B[2][2];
    i32x4 acc[8][4] = {};

    // ---- prologue: region0 -> buf0, region1 -> buf1 ----
    #pragma unroll
    for (int R = 0; R < 4; ++R) { STAGE_A(0, R, 0); STAGE_B(0, R, 0); }
    #pragma unroll
    for (int R = 0; R < 4; ++R) { STAGE_A(1, R, 1); STAGE_B(1, R, 1); }
    WAIT_VM(8);     // buf0 landed (buf1's 8 still in flight)
    BAR();
    LOAD_B_TO(bfr0, 0, 0);    // b0 nq0
    LOAD_B_TO(b2A, 0, 1);     // b0 nq1
    LOAD_A_TO(afrA, 0, 0);    // b0 h0

    #pragma unroll 1
    for (int it = 0; it < NI; ++it) {
        const int kt1 = 2 * it + 1;
        const int kt2 = (2 * it + 2) & (NT - 1);
        const int kt3 = (2 * it + 3) & (NT - 1);

        // ---- W1: MFMA b0 quads(0,*) [afrA, bfr0, b2A] | read b0 h1 -> afrB
        //          | stage b1 {Br2,r3, Ar1,r3}(kt1)
        LOAD_A_TO(afrB, 0, 1);
        if (it) { STAGE_B(1, 2, kt1); STAGE_B(1, 3, kt1);
                  STAGE_A(1, 1, kt1); STAGE_A(1, 3, kt1); }
        MFMA_Q2(afrA, bfr0, 0, 0);
        MFMA_Q2(afrA, b2A, 0, 1);
        if (it) { WAIT_VM(2); } else { WAIT_VM(0); }
        BAR();

        // ---- W2: MFMA b0 quads(1,*) [afrB, bfr0, b2A] | read b1 h0 -> afrA,
        //          b1 nq1 -> b2B, b1 nq0 -> bfr0 (after Q(1,0))
        //          | stage b0 {Br0,r1, Ar0,r2}(kt2)
        LOAD_A_TO(afrA, 1, 0);
        LOAD_B_TO(b2B, 1, 1);
        STAGE_B(0, 0, kt2); STAGE_B(0, 1, kt2);
        STAGE_A(0, 0, kt2); STAGE_A(0, 2, kt2);
        MFMA_Q2(afrB, bfr0, 1, 0);
        LOAD_B_TO(bfr0, 1, 0);
        MFMA_Q2(afrB, b2A, 1, 1);
        WAIT_VM(4);
        BAR();

        // ---- W3: MFMA b1 quads(0,*) [afrA, bfr0, b2B] | read b1 h1 -> afrB
        //          | stage b0 {Br2,r3, Ar1,r3}(kt2)
        LOAD_A_TO(afrB, 1, 1);
        STAGE_B(0, 2, kt2); STAGE_B(0, 3, kt2);
        STAGE_A(0, 1, kt2); STAGE_A(0, 3, kt2);
        MFMA_Q2(afrA, bfr0, 0, 0);
        MFMA_Q2(afrA, b2B, 0, 1);
        WAIT_VM(2);
        BAR();

        // ---- W4: MFMA b1 quads(1,*) [afrB, bfr0, b2B] | read b0' h0 -> afrA,
        //          b0' nq1 -> b2A, b0' nq0 -> bfr0 (after Q(1,0))
        //          | stage b1 {Br0,r1, Ar0,r2}(kt3)
        LOAD_A_TO(afrA, 0, 0);
        LOAD_B_TO(b2A, 0, 1);
        STAGE_B(1, 0, kt3); STAGE_B(1, 1, kt3);
        STAGE_A(1, 0, kt3); STAGE_A(1, 2, kt3);
        MFMA_Q2(afrB, bfr0, 1, 0);
        LOAD_B_TO(bfr0, 0, 0);
        MFMA_Q2(afrB, b2B, 1, 1);
        WAIT_VM(4);
        BAR();
    }

    // ---- epilogue: y = srow[m]*wscale[n]*acc + wadd[n]*rowsum[m] + bias[n] ----
    #pragma unroll
    for (int n = 0; n < 4; ++n) {
        const int col = n0 + wn * 64 + n * 16 + l15;
        const float sc = wscale[col];
        const float ad = wadd[col];
        const float bi = bias[col];
        #pragma unroll
        for (int m = 0; m < 8; ++m) {
            const int row = m0 + wm * 128 + m * 16 + g * 4;
            const float4 rs4 = *(const float4*)&rowsum[row];
            const float4 sr4 = *(const float4*)&srow[row];
            #pragma unroll
            for (int j = 0; j < 4; ++j) {
                const float rs = (j == 0) ? rs4.x : (j == 1) ? rs4.y : (j == 2) ? rs4.z : rs4.w;
                const float sr = (j == 0) ? sr4.x : (j == 1) ? sr4.y : (j == 2) ? sr4.z : sr4.w;
                out[(size_t)(row + j) * OUT_DIM + col] =
                    (float)acc[m][n][j] * (sc * sr) + ad * rs + bi;
            }
        }
    }
}

// ---------------------------------------------------------------------------
extern "C" void kernel_launch(void* const* d_in, const int* in_sizes, int n_in,
                              void* d_out, int out_size, void* d_ws, size_t ws_size,
                              hipStream_t stream)
{
    const float* x      = (const float*)d_in[0];
    const int*   wp     = (const int*)d_in[1];
    const float* wscale = (const float*)d_in[2];
    const float* wadd   = (const float*)d_in[3];
    const float* bias   = (const float*)d_in[4];
    float*       out    = (float*)d_out;

    const int M = in_sizes[0] / IN_DIM;   // 8192

    // ws layout: [ wf8 i8 N*K | aq i8 M*K | rowsum f32 M | srow f32 M ]
    char* ws = (char*)d_ws;
    signed char* wf8 = (signed char*)ws;
    const size_t wf_bytes = (size_t)OUT_DIM * IN_DIM;
    int* aq = (int*)(ws + wf_bytes);
    const size_t aq_bytes = (size_t)M * IN_DIM;
    float* rowsum = (float*)(ws + wf_bytes + aq_bytes);
    float* srow   = (float*)(ws + wf_bytes + aq_bytes + (size_t)M * 4);

    const int unpack_blocks = (OUT_DIM * (IN_DIM / 8)) / 256;   // 8192
    unpack_w8<<<unpack_blocks, 256, 0, stream>>>(wp, wf8);

    had_rows_q<<<M, 256, 0, stream>>>(x, aq, rowsum, srow);

    gemm_i8<<<(M / 256) * (OUT_DIM / 256), 512, 0, stream>>>(
        (const signed char*)aq, wf8, wscale, wadd, bias, rowsum, srow, out);
}

// Round 11
// 183.738 us; speedup vs baseline: 1.4206x; 1.4206x over previous
//
#include <hip/hip_runtime.h>
#include <hip/hip_bf16.h>
#include <hip/hip_fp16.h>

#define IN_DIM 4096
#define OUT_DIM 4096
#define HAD_SCALE_F 0.08838834764831845f   // 2^-3.5

typedef int   i32x4 __attribute__((ext_vector_type(4)));
typedef float f32x4 __attribute__((ext_vector_type(4)));

// ---------------------------------------------------------------------------
// Kernel A (round-11): wave-shuffle FWHT. Lane l of a wave holds float2 =
// elements (2l, 2l+1) of one 128-block. Stride-1 butterfly in-register;
// strides 2..64 are lane-xor masks 1..32 via __shfl_xor (index bit s <->
// lane bit s/2; upper element iff lane&m; all stages commute). No LDS, no
// syncthreads in the transform (the old version burned ~2 GB of LDS traffic
// over 7 barrier-separated stages). Quantization identical to round 8:
// s_a = rowmax/127, aq int8, rowsum = s_a * sum(q) (self-consistent).
// One 256-thr block per row; each of 4 waves handles 8 blocks.
// ---------------------------------------------------------------------------
__global__ __launch_bounds__(256)
void had_rows_q(const float* __restrict__ x, short* __restrict__ aq,
                float* __restrict__ rowsum, float* __restrict__ srow)
{
    __shared__ float wmx[4];
    __shared__ int   wqs[4];
    const int tid  = threadIdx.x;
    const int lane = tid & 63;
    const int wv   = tid >> 6;          // wave 0..3
    const size_t row = blockIdx.x;
    const float* xr = x + row * IN_DIM;

    float2 v[8];
    #pragma unroll
    for (int b = 0; b < 8; ++b) {
        const int blk = wv * 8 + b;
        v[b] = *(const float2*)&xr[blk * 128 + lane * 2];
    }

    float smax = 0.f;
    #pragma unroll
    for (int b = 0; b < 8; ++b) {
        // stride 1 (in-register)
        const float a = v[b].x + v[b].y;
        const float d = v[b].x - v[b].y;
        v[b].x = a; v[b].y = d;
        // strides 2..64 -> lane-xor 1..32
        #pragma unroll
        for (int m = 1; m <= 32; m <<= 1) {
            const float px = __shfl_xor(v[b].x, m, 64);
            const float py = __shfl_xor(v[b].y, m, 64);
            const float s  = (lane & m) ? -1.0f : 1.0f;
            v[b].x = fmaf(s, v[b].x, px);
            v[b].y = fmaf(s, v[b].y, py);
        }
        v[b].x *= HAD_SCALE_F;
        v[b].y *= HAD_SCALE_F;
        smax = fmaxf(smax, fmaxf(fabsf(v[b].x), fabsf(v[b].y)));
    }

    // row absmax: wave reduce + cross-wave via LDS
    #pragma unroll
    for (int off = 32; off > 0; off >>= 1)
        smax = fmaxf(smax, __shfl_xor(smax, off, 64));
    if (lane == 0) wmx[wv] = smax;
    __syncthreads();
    const float mx  = fmaxf(fmaxf(wmx[0], wmx[1]), fmaxf(wmx[2], wmx[3]));
    const float inv = (mx > 0.f) ? 127.0f / mx : 0.f;
    const float sa  = mx * (1.0f / 127.0f);

    // quantize + pack (byte0 = even elem, byte1 = odd elem) + integer row sum
    int qsum = 0;
    #pragma unroll
    for (int b = 0; b < 8; ++b) {
        const int blk = wv * 8 + b;
        const int q0 = (int)rintf(v[b].x * inv);
        const int q1 = (int)rintf(v[b].y * inv);
        qsum += q0 + q1;
        aq[(row * IN_DIM + blk * 128 + lane * 2) >> 1] =
            (short)((q0 & 0xFF) | ((q1 & 0xFF) << 8));
    }
    #pragma unroll
    for (int off = 32; off > 0; off >>= 1) qsum += __shfl_xor(qsum, off, 64);
    if (lane == 0) wqs[wv] = qsum;
    __syncthreads();
    if (tid == 0) {
        rowsum[row] = sa * (float)((wqs[0] + wqs[1]) + (wqs[2] + wqs[3]));
        srow[row]   = sa;
    }
}

// ---------------------------------------------------------------------------
// Kernel B: unpack int4 nibbles -> int8 weight matrix [OUT][IN] row-major.
// ---------------------------------------------------------------------------
__global__ __launch_bounds__(256)
void unpack_w8(const int* __restrict__ wp, signed char* __restrict__ wf8)
{
    const int gid = blockIdx.x * 256 + threadIdx.x;
    const int n   = gid >> 9;
    const int k0  = (gid & 511) * 8;
    const int4 p  = *(const int4*)(wp + (size_t)n * (IN_DIM / 2) + (k0 >> 1));
    const unsigned lo = (unsigned)(p.x & 15) | ((unsigned)((p.x >> 4) & 15) << 8)
                      | ((unsigned)(p.y & 15) << 16) | ((unsigned)((p.y >> 4) & 15) << 24);
    const unsigned hi = (unsigned)(p.z & 15) | ((unsigned)((p.z >> 4) & 15) << 8)
                      | ((unsigned)(p.w & 15) << 16) | ((unsigned)((p.w >> 4) & 15) << 24);
    *(uint2*)(wf8 + (size_t)n * IN_DIM + k0) = make_uint2(lo, hi);
}

// ---------------------------------------------------------------------------
// Kernel C: 256x256 int8 GEMM — ROUND-8 VERBATIM (best verified: 135.6 µs,
// MfmaUtil 44%, 0 bank conflicts). Round 10's full register pipelining
// spilled (~300 regs > 256 budget, WRITE_SIZE +66 MB scratch); reverted.
// 4-window schedule, half-pipelined B nq1, vm counts W1:2/0 W2:4 W3:2 W4:4.
// ---------------------------------------------------------------------------
#define NT (IN_DIM / 128)   // 32 K-regions
#define NI (NT / 2)         // 16 iterations, 2 regions each

#define BAR()        asm volatile("s_barrier" ::: "memory")
#define WAIT_VM(N)   asm volatile("s_waitcnt vmcnt(" #N ")" ::: "memory")

// LDS: A0 @ 0, B0 @ 32768, A1 @ 65536, B1 @ 98304 (each 32 KiB = 256 rows x 128 B)
#define STAGE_A(p, R, kt) __builtin_amdgcn_global_load_lds( \
    (const __attribute__((address_space(1))) void*)(sA + (((size_t)(R)) << 18) + (((size_t)((kt) & 31)) << 7)), \
    (__attribute__((address_space(3))) void*)(smem + (p) * 65536 + (R) * 8192 + dstA), 16, 0, 0)
#define STAGE_B(p, R, kt) __builtin_amdgcn_global_load_lds( \
    (const __attribute__((address_space(1))) void*)(sB + (((size_t)(R)) << 18) + (((size_t)((kt) & 31)) << 7)), \
    (__attribute__((address_space(3))) void*)(smem + (p) * 65536 + (R) * 8192 + dstB), 16, 0, 0)

#define LDA(p, mq, mi, kb) (*(const i32x4*)(smem + (p)*65536 + (mq)*8192 + (mi)*2048 + aOffK[kb]))
#define LDB(p, nq, ni, kb) (*(const i32x4*)(smem + (p)*65536 + (nq)*4096 + (ni)*2048 + bOffK[kb]))

#define LOAD_A_TO(dst, p, mq) do { \
    _Pragma("unroll") for (int mi = 0; mi < 4; ++mi) { \
        dst[mi][0] = LDA(p, mq, mi, 0); \
        dst[mi][1] = LDA(p, mq, mi, 1); \
    } } while (0)

#define LOAD_B(p, nq) do { \
    _Pragma("unroll") for (int ni = 0; ni < 2; ++ni) { \
        bfr[(nq)*2+ni][0] = LDB(p, nq, ni, 0); \
        bfr[(nq)*2+ni][1] = LDB(p, nq, ni, 1); \
    } } while (0)

#define MFMA_Q(abuf, mq, nq) do { \
    __builtin_amdgcn_s_setprio(1); \
    _Pragma("unroll") for (int mi = 0; mi < 4; ++mi) \
    _Pragma("unroll") for (int ni = 0; ni < 2; ++ni) \
    _Pragma("unroll") for (int kb = 0; kb < 2; ++kb) \
        acc[(mq)*4+mi][(nq)*2+ni] = __builtin_amdgcn_mfma_i32_16x16x64_i8( \
            abuf[mi][kb], bfr[(nq)*2+ni][kb], acc[(mq)*4+mi][(nq)*2+ni], 0, 0, 0); \
    __builtin_amdgcn_s_setprio(0); \
} while (0)

__global__ __launch_bounds__(512, 2)
void gemm_i8(const signed char* __restrict__ Aq, const signed char* __restrict__ Bw,
             const float* __restrict__ wscale, const float* __restrict__ wadd,
             const float* __restrict__ bias, const float* __restrict__ rowsum,
             const float* __restrict__ srow, float* __restrict__ out)
{
    __shared__ char smem[131072];

    const int tid  = threadIdx.x;
    const int lane = tid & 63;
    const int w    = tid >> 6;     // wave 0..7
    const int wm   = w >> 2;       // 0..1
    const int wn   = w & 3;        // 0..3

    // XCD-aware bijective swizzle: 512 wgs, 8 XCDs, 64 per XCD
    const int bid = blockIdx.x;
    const int wg  = (bid & 7) * 64 + (bid >> 3);
    const int m0  = (wg >> 4) * 256;   // M/256 = 32
    const int n0  = (wg & 15) * 256;   // N/256 = 16

    // ---- staging addresses (pre-swizzled source, linear LDS dest) ----
    const int rt = tid >> 3;
    const int ct = (tid & 7) ^ (rt & 7);
    const signed char* sA = Aq + (size_t)(m0 + rt) * IN_DIM + ct * 16;
    const signed char* sB = Bw + (size_t)(n0 + rt) * IN_DIM + ct * 16;
    const int dstA = w * 1024;
    const int dstB = 32768 + w * 1024;

    // ---- fragment read offsets (swizzled) ----
    const int l15 = lane & 15, g = lane >> 4, l7 = lane & 7;
    const int s0 = (g ^ l7) << 4;
    int aOffK[2], bOffK[2];
    aOffK[0] = (wm * 128 + l15) * 128 + s0;
    aOffK[1] = (wm * 128 + l15) * 128 + (s0 ^ 64);
    bOffK[0] = 32768 + (wn * 64 + l15) * 128 + s0;
    bOffK[1] = 32768 + (wn * 64 + l15) * 128 + (s0 ^ 64);

    i32x4 afrA[4][2], afrB[4][2], bfr[4][2];
    i32x4 acc[8][4] = {};

    // ---- prologue: region0 -> buf0, region1 -> buf1 ----
    #pragma unroll
    for (int R = 0; R < 4; ++R) { STAGE_A(0, R, 0); STAGE_B(0, R, 0); }
    #pragma unroll
    for (int R = 0; R < 4; ++R) { STAGE_A(1, R, 1); STAGE_B(1, R, 1); }
    WAIT_VM(8);
    BAR();
    LOAD_B(0, 0);
    LOAD_A_TO(afrA, 0, 0);

    #pragma unroll 1
    for (int it = 0; it < NI; ++it) {
        const int kt1 = 2 * it + 1;
        const int kt2 = (2 * it + 2) & (NT - 1);
        const int kt3 = (2 * it + 3) & (NT - 1);

        // ---- W1: MFMA b0 quads(0,*) | read b0 nq1,h1 | stage b1 {Br2,r3, Ar1,r3}(kt1)
        LOAD_B(0, 1);
        if (it) { STAGE_B(1, 2, kt1); STAGE_B(1, 3, kt1);
                  STAGE_A(1, 1, kt1); STAGE_A(1, 3, kt1); }
        MFMA_Q(afrA, 0, 0);
        LOAD_A_TO(afrB, 0, 1);
        MFMA_Q(afrA, 0, 1);
        if (it) { WAIT_VM(2); } else { WAIT_VM(0); }
        BAR();

        // ---- W2: MFMA b0 quads(1,*) | read b1 nq0,h0 | stage b0 {Br0,r1, Ar0,r2}(kt2)
        STAGE_B(0, 0, kt2); STAGE_B(0, 1, kt2);
        MFMA_Q(afrB, 1, 0);
        LOAD_B(1, 0);
        LOAD_A_TO(afrA, 1, 0);
        STAGE_A(0, 0, kt2); STAGE_A(0, 2, kt2);
        MFMA_Q(afrB, 1, 1);
        WAIT_VM(4);
        BAR();

        // ---- W3: MFMA b1 quads(0,*) | read b1 nq1,h1 | stage b0 {Br2,r3, Ar1,r3}(kt2)
        STAGE_B(0, 2, kt2); STAGE_B(0, 3, kt2);
        MFMA_Q(afrA, 0, 0);
        LOAD_B(1, 1);
        LOAD_A_TO(afrB, 1, 1);
        STAGE_A(0, 1, kt2); STAGE_A(0, 3, kt2);
        MFMA_Q(afrA, 0, 1);
        WAIT_VM(2);
        BAR();

        // ---- W4: MFMA b1 quads(1,*) | read b0' nq0,h0 | stage b1 {Br0,r1, Ar0,r2}(kt3)
        STAGE_B(1, 0, kt3); STAGE_B(1, 1, kt3);
        MFMA_Q(afrB, 1, 0);
        LOAD_B(0, 0);
        LOAD_A_TO(afrA, 0, 0);
        STAGE_A(1, 0, kt3); STAGE_A(1, 2, kt3);
        MFMA_Q(afrB, 1, 1);
        WAIT_VM(4);
        BAR();
    }

    // ---- epilogue: y = srow[m]*wscale[n]*acc + wadd[n]*rowsum[m] + bias[n] ----
    #pragma unroll
    for (int n = 0; n < 4; ++n) {
        const int col = n0 + wn * 64 + n * 16 + l15;
        const float sc = wscale[col];
        const float ad = wadd[col];
        const float bi = bias[col];
        #pragma unroll
        for (int m = 0; m < 8; ++m) {
            const int row = m0 + wm * 128 + m * 16 + g * 4;
            const float4 rs4 = *(const float4*)&rowsum[row];
            const float4 sr4 = *(const float4*)&srow[row];
            #pragma unroll
            for (int j = 0; j < 4; ++j) {
                const float rs = (j == 0) ? rs4.x : (j == 1) ? rs4.y : (j == 2) ? rs4.z : rs4.w;
                const float sr = (j == 0) ? sr4.x : (j == 1) ? sr4.y : (j == 2) ? sr4.z : sr4.w;
                out[(size_t)(row + j) * OUT_DIM + col] =
                    (float)acc[m][n][j] * (sc * sr) + ad * rs + bi;
            }
        }
    }
}

// ---------------------------------------------------------------------------
extern "C" void kernel_launch(void* const* d_in, const int* in_sizes, int n_in,
                              void* d_out, int out_size, void* d_ws, size_t ws_size,
                              hipStream_t stream)
{
    const float* x      = (const float*)d_in[0];
    const int*   wp     = (const int*)d_in[1];
    const float* wscale = (const float*)d_in[2];
    const float* wadd   = (const float*)d_in[3];
    const float* bias   = (const float*)d_in[4];
    float*       out    = (float*)d_out;

    const int M = in_sizes[0] / IN_DIM;   // 8192

    // ws layout: [ wf8 i8 N*K | aq i8 M*K | rowsum f32 M | srow f32 M ]
    char* ws = (char*)d_ws;
    signed char* wf8 = (signed char*)ws;
    const size_t wf_bytes = (size_t)OUT_DIM * IN_DIM;
    short* aq = (short*)(ws + wf_bytes);
    const size_t aq_bytes = (size_t)M * IN_DIM;
    float* rowsum = (float*)(ws + wf_bytes + aq_bytes);
    float* srow   = (float*)(ws + wf_bytes + aq_bytes + (size_t)M * 4);

    const int unpack_blocks = (OUT_DIM * (IN_DIM / 8)) / 256;   // 8192
    unpack_w8<<<unpack_blocks, 256, 0, stream>>>(wp, wf8);

    had_rows_q<<<M, 256, 0, stream>>>(x, aq, rowsum, srow);

    gemm_i8<<<(M / 256) * (OUT_DIM / 256), 512, 0, stream>>>(
        (const signed char*)aq, wf8, wscale, wadd, bias, rowsum, srow, out);
}